// Round 1
// baseline (747.158 us; speedup 1.0000x reference)
//
#include <hip/hip_runtime.h>
#include <math.h>

// Problem constants (from reference): x (4,64,64,256) f32, offset_w (3,3,256,27),
// offset_b (27), dcn_weight (256,256,3,3). Out: (4,64,64,256) f32.
#define P_TOTAL 16384      // 4*64*64 pixels
#define WR_OFF  0          // ws float offset: W_r [2304][256]
#define OM_OFF  589824     // ws float offset: om  [16384][27]

// W_r[(c*9+k)*256 + oc] = dcn_weight[oc][c][k/3][k%3]
__global__ void transpose_w(const float* __restrict__ dcn_w, float* __restrict__ w_r) {
    int o = blockIdx.x * 256 + threadIdx.x;     // o < 2304*256
    int row = o >> 8;
    int oc  = o & 255;
    int c = row / 9;
    int k = row - 9 * c;
    w_r[o] = dcn_w[(oc * 256 + c) * 9 + k];
}

// om[p][oc] = sum_{ky,kx,c} x[n,y+ky-1,w+kx-1,c] * offset_w[ky,kx,c,oc] + b[oc]
__global__ __launch_bounds__(256) void offset_conv(const float* __restrict__ x,
                                                   const float* __restrict__ ow,
                                                   const float* __restrict__ ob,
                                                   float* __restrict__ om) {
    int tid  = threadIdx.x;
    int oc   = tid & 31;            // 32 slots, 27 active
    int psub = tid >> 5;            // 8 pixels per block
    int p = blockIdx.x * 8 + psub;
    int n = p >> 12;
    int rem = p & 4095;
    int y = rem >> 6;
    int w = rem & 63;
    int oce = oc < 27 ? oc : 26;    // clamp so inactive lanes stay in-bounds
    float acc = ob[oce];
    for (int ky = 0; ky < 3; ++ky) {
        int yy = y + ky - 1;
        if (yy < 0 || yy > 63) continue;
        for (int kx = 0; kx < 3; ++kx) {
            int xx = w + kx - 1;
            if (xx < 0 || xx > 63) continue;
            const float* xr = x + ((n * 64 + yy) * 64 + xx) * 256;
            const float* wr = ow + (ky * 3 + kx) * 256 * 27 + oce;
            #pragma unroll 4
            for (int c = 0; c < 256; c += 4) {
                float4 xv = *(const float4*)(xr + c);
                acc = fmaf(xv.x, wr[(c + 0) * 27], acc);
                acc = fmaf(xv.y, wr[(c + 1) * 27], acc);
                acc = fmaf(xv.z, wr[(c + 2) * 27], acc);
                acc = fmaf(xv.w, wr[(c + 3) * 27], acc);
            }
        }
    }
    if (oc < 27) om[p * 27 + oc] = acc;
}

// Fused bilinear sampling + GEMM. Block: 16 pixels x 256 oc (256 threads).
__global__ __launch_bounds__(256) void dcn_main(const float* __restrict__ x,
                                                const float* __restrict__ om,
                                                const float* __restrict__ w_r,
                                                float* __restrict__ out) {
    __shared__ float s_ly[16][9], s_lx[16][9], s_m[16][9];
    __shared__ int   s_y1[16][9], s_x1[16][9];
    __shared__ float s_val[16][256];

    int tid = threadIdx.x;
    int p0  = blockIdx.x * 16;
    int n    = p0 >> 12;
    int rem0 = p0 & 4095;
    int y    = rem0 >> 6;
    int w0   = rem0 & 63;

    // Phase A: tap parameters (144 jobs)
    if (tid < 144) {
        int ps = tid / 9, k = tid % 9;
        int p = p0 + ps;
        int wpix = w0 + ps;
        float offy = om[p * 27 + 2 * k];
        float offx = om[p * 27 + 2 * k + 1];
        float mraw = om[p * 27 + 18 + k];
        float mask = 1.f / (1.f + expf(-mraw));
        float py = (float)(y + 1)    + (float)(k / 3 - 1) + offy;
        float px = (float)(wpix + 1) + (float)(k % 3 - 1) + offx;
        py = fminf(fmaxf(py, 0.f), 65.f);   // padded coords [0, 65]
        px = fminf(fmaxf(px, 0.f), 65.f);
        float y1f = floorf(py), x1f = floorf(px);
        s_y1[ps][k] = (int)y1f - 1;         // unpadded top-left row
        s_x1[ps][k] = (int)x1f - 1;
        s_ly[ps][k] = py - y1f;
        s_lx[ps][k] = px - x1f;
        s_m [ps][k] = mask;
    }
    __syncthreads();

    float acc[16];
    #pragma unroll
    for (int i = 0; i < 16; ++i) acc[i] = 0.f;
    int oc = tid;

    for (int k = 0; k < 9; ++k) {
        // Phase B: stage masked bilinear samples for this tap, c = tid
        int c = tid;
        const float* xn = x + n * 4096 * 256 + c;
        #pragma unroll 4
        for (int ps = 0; ps < 16; ++ps) {
            int ya = s_y1[ps][k], xa = s_x1[ps][k];
            float ly = s_ly[ps][k], lx = s_lx[ps][k], m = s_m[ps][k];
            float hy = 1.f - ly, hx = 1.f - lx;
            bool yav = (unsigned)ya       < 64u;
            bool ybv = (unsigned)(ya + 1) < 64u;
            bool xav = (unsigned)xa       < 64u;
            bool xbv = (unsigned)(xa + 1) < 64u;
            float v1 = (yav && xav) ? xn[((ya)     * 64 + xa)     * 256] : 0.f;
            float v2 = (yav && xbv) ? xn[((ya)     * 64 + xa + 1) * 256] : 0.f;
            float v3 = (ybv && xav) ? xn[((ya + 1) * 64 + xa)     * 256] : 0.f;
            float v4 = (ybv && xbv) ? xn[((ya + 1) * 64 + xa + 1) * 256] : 0.f;
            s_val[ps][c] = m * (hy * hx * v1 + hy * lx * v2 + ly * hx * v3 + ly * lx * v4);
        }
        __syncthreads();

        // Phase C: GEMM slice. W_r row (c*9+k), col oc.
        const float* wrk = w_r + k * 256 + oc;
        #pragma unroll 2
        for (int c4 = 0; c4 < 64; ++c4) {
            int cc = c4 * 4;
            float wv0 = wrk[(cc + 0) * 2304];
            float wv1 = wrk[(cc + 1) * 2304];
            float wv2 = wrk[(cc + 2) * 2304];
            float wv3 = wrk[(cc + 3) * 2304];
            #pragma unroll
            for (int ps = 0; ps < 16; ++ps) {
                float4 v = *(const float4*)&s_val[ps][cc];
                acc[ps] = fmaf(v.x, wv0, fmaf(v.y, wv1, fmaf(v.z, wv2, fmaf(v.w, wv3, acc[ps]))));
            }
        }
        __syncthreads();
    }

    #pragma unroll
    for (int ps = 0; ps < 16; ++ps)
        out[(p0 + ps) * 256 + oc] = acc[ps];
}

extern "C" void kernel_launch(void* const* d_in, const int* in_sizes, int n_in,
                              void* d_out, int out_size, void* d_ws, size_t ws_size,
                              hipStream_t stream) {
    const float* x  = (const float*)d_in[0];
    const float* ow = (const float*)d_in[1];
    const float* ob = (const float*)d_in[2];
    const float* dw = (const float*)d_in[3];
    float* ws  = (float*)d_ws;
    float* w_r = ws + WR_OFF;
    float* om  = ws + OM_OFF;
    float* out = (float*)d_out;

    hipLaunchKernelGGL(transpose_w, dim3(2304), dim3(256), 0, stream, dw, w_r);
    hipLaunchKernelGGL(offset_conv, dim3(2048), dim3(256), 0, stream, x, ow, ob, om);
    hipLaunchKernelGGL(dcn_main,    dim3(1024), dim3(256), 0, stream, x, om, w_r, out);
}

// Round 2
// 210.305 us; speedup vs baseline: 3.5527x; 3.5527x over previous
//
#include <hip/hip_runtime.h>
#include <math.h>

typedef __attribute__((ext_vector_type(8))) short bf16x8;
typedef __attribute__((ext_vector_type(4))) float f32x4;

// x (4,64,64,256) f32 | offset_w (3,3,256,27) | offset_b (27) | dcn_weight (256,256,3,3)
// out (4,64,64,256) f32
// ws layout (bytes):
#define WT_OFF   0                       // W_t  bf16 [256 oc][2304 k], k = t*256+c
#define WT_BYTES (2304*256*2)            // 1179648
#define WOT_OFF  WT_BYTES                // W_o_t bf16 [32 oc][2304 k]
#define WOT_BYTES (2304*32*2)            // 147456
#define OM_OFF   (WOT_OFF + WOT_BYTES)   // om f32 [16384][32]  (16B aligned)

static __device__ __forceinline__ unsigned short f2bf(float f) {
    unsigned u = __float_as_uint(f);
    unsigned r = (u + 0x7fffu + ((u >> 16) & 1u)) >> 16;   // RNE
    return (unsigned short)r;
}

// W_t[oc][t*256+c] = bf16(dcn_w[oc][c][t])   (dcn_w flat: [oc*2304 + c*9 + t])
__global__ void prep_wt(const float* __restrict__ dw, unsigned short* __restrict__ wt) {
    int oc = blockIdx.x;      // 256
    int c  = threadIdx.x;     // 256
    const float* src = dw + oc * 2304 + c * 9;
    unsigned short* dst = wt + oc * 2304 + c;
    #pragma unroll
    for (int t = 0; t < 9; ++t) dst[t * 256] = f2bf(src[t]);
}

// W_o_t[oc][t*256+c] = bf16(offset_w[(t*256+c)*27 + oc]), oc>=27 -> 0
__global__ void prep_wot(const float* __restrict__ ow, unsigned short* __restrict__ wot) {
    int g = blockIdx.x * 256 + threadIdx.x;   // < 73728
    int oc = g & 31;
    int idx = g >> 5;                          // t*256+c
    float v = (oc < 27) ? ow[idx * 27 + oc] : 0.f;
    wot[oc * 2304 + idx] = f2bf(v);
}

// offset conv via MFMA: om[p][0..26] = conv3x3(x, offset_w) + bias. 32 px/block.
__global__ __launch_bounds__(256) void offset_mfma(const float* __restrict__ x,
        const unsigned short* __restrict__ wot, const float* __restrict__ ob,
        float* __restrict__ om) {
    __shared__ unsigned int s_x[32 * 128];   // [32 px][256 c] bf16, XOR-swizzled

    int tid  = threadIdx.x;
    int lane = tid & 63;
    int wave = tid >> 6;
    int p0 = blockIdx.x * 32;
    int n  = p0 >> 12;
    int y  = (p0 & 4095) >> 6;     // uniform per block (32 | 64-wide rows)
    int w0 = p0 & 63;
    const float* xn = x + (size_t)n * 4096 * 256;

    int cpair = tid & 127;          // c = 2*cpair
    int half  = tid >> 7;           // px 16-group

    int m  = wave & 1;              // A row-frag
    int nb = wave >> 1;             // B col-frag
    f32x4 acc = {0.f, 0.f, 0.f, 0.f};

    int arow  = m * 16 + (lane & 15);
    int klane = (lane >> 4) * 8;
    const unsigned short* bbase = wot + (nb * 16 + (lane & 15)) * 2304 + klane;

    for (int t = 0; t < 9; ++t) {
        int ty = t / 3, tx = t - 3 * ty;
        int yy = y + ty - 1;
        bool yok = (unsigned)yy < 64u;
        __syncthreads();                          // prev readers done
        #pragma unroll 4
        for (int ps = 0; ps < 16; ++ps) {
            int px = half * 16 + ps;
            int xx = w0 + px + tx - 1;
            float2 v = make_float2(0.f, 0.f);
            if (yok && (unsigned)xx < 64u)
                v = *(const float2*)(xn + ((yy * 64 + xx) * 256 + cpair * 2));
            unsigned u = (unsigned)f2bf(v.x) | ((unsigned)f2bf(v.y) << 16);
            s_x[px * 128 + (cpair ^ ((px & 7) << 2))] = u;
        }
        __syncthreads();
        const unsigned short* bp = bbase + t * 256;
        #pragma unroll
        for (int c0 = 0; c0 < 256; c0 += 32) {
            int kb = (c0 + klane) * 2;
            bf16x8 a = *(const bf16x8*)((const char*)s_x + arow * 512 + (kb ^ ((arow & 7) << 4)));
            bf16x8 b = *(const bf16x8*)(bp + c0);
            acc = __builtin_amdgcn_mfma_f32_16x16x32_bf16(a, b, acc, 0, 0, 0);
        }
    }

    int col = nb * 16 + (lane & 15);
    float bias = (col < 27) ? ob[col] : 0.f;
    int rbase = m * 16 + (lane >> 4) * 4;
    #pragma unroll
    for (int j = 0; j < 4; ++j)
        om[(size_t)(p0 + rbase + j) * 32 + col] = acc[j] + bias;
}

// Fused bilinear-sample + GEMM via MFMA. 32 px x 256 oc per block, 4 waves.
__global__ __launch_bounds__(256) void dcn_mfma(const float* __restrict__ x,
        const float* __restrict__ om, const unsigned short* __restrict__ wt,
        float* __restrict__ out) {
    __shared__ unsigned int s_v[32 * 128];        // [32 px][256 c] bf16, XOR-swizzled
    __shared__ float s_ly[32][9], s_lx[32][9], s_m[32][9];
    __shared__ int   s_y1[32][9], s_x1[32][9];

    int tid  = threadIdx.x;
    int lane = tid & 63;
    int wave = tid >> 6;
    int p0 = blockIdx.x * 32;
    int n  = p0 >> 12;
    int y  = (p0 & 4095) >> 6;
    int w0 = p0 & 63;
    const float* xn = x + (size_t)n * 4096 * 256;

    // Phase A: tap params (32 px x 9 taps)
    for (int j = tid; j < 288; j += 256) {
        int ps = j / 9;
        int k  = j - 9 * ps;
        int p  = p0 + ps;
        float offy = om[(size_t)p * 32 + 2 * k];
        float offx = om[(size_t)p * 32 + 2 * k + 1];
        float mraw = om[(size_t)p * 32 + 18 + k];
        float mask = 1.f / (1.f + __expf(-mraw));
        float py = (float)(y + 1)       + (float)(k / 3 - 1) + offy;
        float px = (float)(w0 + ps + 1) + (float)(k % 3 - 1) + offx;
        py = fminf(fmaxf(py, 0.f), 65.f);
        px = fminf(fmaxf(px, 0.f), 65.f);
        float y1f = floorf(py), x1f = floorf(px);
        s_y1[ps][k] = (int)y1f - 1;
        s_x1[ps][k] = (int)x1f - 1;
        s_ly[ps][k] = py - y1f;
        s_lx[ps][k] = px - x1f;
        s_m [ps][k] = mask;
    }

    int cpair = tid & 127;
    int half  = tid >> 7;
    f32x4 acc[2][4];
    #pragma unroll
    for (int m = 0; m < 2; ++m)
        #pragma unroll
        for (int nb = 0; nb < 4; ++nb)
            acc[m][nb] = (f32x4){0.f, 0.f, 0.f, 0.f};

    int arow  = lane & 15;
    int klane = (lane >> 4) * 8;
    const unsigned short* bbase = wt + (size_t)(wave * 64 + (lane & 15)) * 2304 + klane;

    __syncthreads();    // Phase A visible

    for (int t = 0; t < 9; ++t) {
        // Phase B: stage masked bilinear V-tile for tap t
        #pragma unroll 2
        for (int ps = 0; ps < 16; ++ps) {
            int px = half * 16 + ps;
            int ya = s_y1[px][t], xa = s_x1[px][t];
            float ly = s_ly[px][t], lx = s_lx[px][t], mk = s_m[px][t];
            float hy = 1.f - ly, hx = 1.f - lx;
            const float* base = xn + cpair * 2;
            bool yav = (unsigned)ya       < 64u;
            bool ybv = (unsigned)(ya + 1) < 64u;
            bool xav = (unsigned)xa       < 64u;
            bool xbv = (unsigned)(xa + 1) < 64u;
            float2 z = make_float2(0.f, 0.f);
            float2 v1 = (yav && xav) ? *(const float2*)(base + ((ya)     * 64 + xa)     * 256) : z;
            float2 v2 = (yav && xbv) ? *(const float2*)(base + ((ya)     * 64 + xa + 1) * 256) : z;
            float2 v3 = (ybv && xav) ? *(const float2*)(base + ((ya + 1) * 64 + xa)     * 256) : z;
            float2 v4 = (ybv && xbv) ? *(const float2*)(base + ((ya + 1) * 64 + xa + 1) * 256) : z;
            float w11 = hy * hx, w12 = hy * lx, w21 = ly * hx, w22 = ly * lx;
            float r0 = mk * (w11 * v1.x + w12 * v2.x + w21 * v3.x + w22 * v4.x);
            float r1 = mk * (w11 * v1.y + w12 * v2.y + w21 * v3.y + w22 * v4.y);
            unsigned u = (unsigned)f2bf(r0) | ((unsigned)f2bf(r1) << 16);
            s_v[px * 128 + (cpair ^ ((px & 7) << 2))] = u;
        }
        __syncthreads();
        // Phase C: 8 K-steps x 8 mfma
        const unsigned short* bp = bbase + t * 256;
        #pragma unroll
        for (int c0 = 0; c0 < 256; c0 += 32) {
            int kb = (c0 + klane) * 2;
            int sw = (arow & 7) << 4;
            bf16x8 a0 = *(const bf16x8*)((const char*)s_v + arow * 512        + (kb ^ sw));
            bf16x8 a1 = *(const bf16x8*)((const char*)s_v + (arow + 16) * 512 + (kb ^ sw));
            #pragma unroll
            for (int nb = 0; nb < 4; ++nb) {
                bf16x8 b = *(const bf16x8*)(bp + (size_t)nb * 16 * 2304 + c0);
                acc[0][nb] = __builtin_amdgcn_mfma_f32_16x16x32_bf16(a0, b, acc[0][nb], 0, 0, 0);
                acc[1][nb] = __builtin_amdgcn_mfma_f32_16x16x32_bf16(a1, b, acc[1][nb], 0, 0, 0);
            }
        }
        __syncthreads();
    }

    // Epilogue: C/D layout col=lane&15, row=(lane>>4)*4+j  [m89]
    int rj = (lane >> 4) * 4;
    int cb = wave * 64 + (lane & 15);
    #pragma unroll
    for (int m = 0; m < 2; ++m)
        #pragma unroll
        for (int nb = 0; nb < 4; ++nb)
            #pragma unroll
            for (int j = 0; j < 4; ++j)
                out[(size_t)(p0 + m * 16 + rj + j) * 256 + cb + nb * 16] = acc[m][nb][j];
}

extern "C" void kernel_launch(void* const* d_in, const int* in_sizes, int n_in,
                              void* d_out, int out_size, void* d_ws, size_t ws_size,
                              hipStream_t stream) {
    const float* x  = (const float*)d_in[0];
    const float* ow = (const float*)d_in[1];
    const float* ob = (const float*)d_in[2];
    const float* dw = (const float*)d_in[3];
    unsigned short* wt  = (unsigned short*)((char*)d_ws + WT_OFF);
    unsigned short* wot = (unsigned short*)((char*)d_ws + WOT_OFF);
    float*          omp = (float*)((char*)d_ws + OM_OFF);
    float* out = (float*)d_out;

    hipLaunchKernelGGL(prep_wt,     dim3(256), dim3(256), 0, stream, dw, wt);
    hipLaunchKernelGGL(prep_wot,    dim3(288), dim3(256), 0, stream, ow, wot);
    hipLaunchKernelGGL(offset_mfma, dim3(512), dim3(256), 0, stream, x, wot, ob, omp);
    hipLaunchKernelGGL(dcn_mfma,    dim3(512), dim3(256), 0, stream, x, omp, wt, out);
}

// Round 3
// 199.815 us; speedup vs baseline: 3.7393x; 1.0525x over previous
//
#include <hip/hip_runtime.h>
#include <math.h>

typedef __attribute__((ext_vector_type(8))) short bf16x8;
typedef __attribute__((ext_vector_type(4))) float f32x4;

// x (4,64,64,256) f32 | offset_w (3,3,256,27) | offset_b (27) | dcn_weight (256,256,3,3)
// out (4,64,64,256) f32
// ws layout (bytes):
#define XP_OFF   0                        // x_p bf16 [4][67][67][256]  pad: top/left 1, bot/right 2
#define XP_BYTES (4*67*67*256*2)          // 9,193,472
#define WT_OFF   XP_BYTES                 // W_t  bf16 [256 oc][2304 k], k = t*256+c
#define WT_BYTES (2304*256*2)             // 1,179,648
#define WOT_OFF  (WT_OFF + WT_BYTES)      // W_o_t bf16 [32 oc][2304 k]
#define WOT_BYTES (2304*32*2)             // 147,456
#define OM_OFF   (WOT_OFF + WOT_BYTES)    // om f32 [16384][32]

static __device__ __forceinline__ unsigned short f2bf(float f) {
    unsigned u = __float_as_uint(f);
    unsigned r = (u + 0x7fffu + ((u >> 16) & 1u)) >> 16;   // RNE
    return (unsigned short)r;
}
static __device__ __forceinline__ float bflo(unsigned u) { return __uint_as_float(u << 16); }
static __device__ __forceinline__ float bfhi(unsigned u) { return __uint_as_float(u & 0xffff0000u); }

// x_p[n][yy][xx][c] = bf16(x[n][yy-1][xx-1][c]) for 1<=yy,xx<=64 else 0
__global__ __launch_bounds__(256) void prep_xpad(const float* __restrict__ x,
                                                 unsigned short* __restrict__ xp) {
    int g = blockIdx.x * 256 + threadIdx.x;
    if (g >= 17956 * 32) return;
    int row = g >> 5, sub = g & 31;          // 8 ch per thread
    int n = row / 4489, rem = row - n * 4489;
    int yy = rem / 67,  xx = rem - yy * 67;
    unsigned short* dst = xp + (size_t)row * 256 + sub * 8;
    unsigned int o[4] = {0u, 0u, 0u, 0u};
    if (yy >= 1 && yy <= 64 && xx >= 1 && xx <= 64) {
        const float* src = x + (((size_t)n * 64 + (yy - 1)) * 64 + (xx - 1)) * 256 + sub * 8;
        float4 a = *(const float4*)src;
        float4 b = *(const float4*)(src + 4);
        o[0] = (unsigned)f2bf(a.x) | ((unsigned)f2bf(a.y) << 16);
        o[1] = (unsigned)f2bf(a.z) | ((unsigned)f2bf(a.w) << 16);
        o[2] = (unsigned)f2bf(b.x) | ((unsigned)f2bf(b.y) << 16);
        o[3] = (unsigned)f2bf(b.z) | ((unsigned)f2bf(b.w) << 16);
    }
    *(uint4*)dst = make_uint4(o[0], o[1], o[2], o[3]);
}

// W_t[oc][t*256+c] = bf16(dcn_w[oc][c][t])
__global__ void prep_wt(const float* __restrict__ dw, unsigned short* __restrict__ wt) {
    int oc = blockIdx.x, c = threadIdx.x;
    const float* src = dw + oc * 2304 + c * 9;
    unsigned short* dst = wt + oc * 2304 + c;
    #pragma unroll
    for (int t = 0; t < 9; ++t) dst[t * 256] = f2bf(src[t]);
}

// W_o_t[oc][t*256+c] = bf16(offset_w[(t*256+c)*27 + oc]), oc>=27 -> 0
__global__ void prep_wot(const float* __restrict__ ow, unsigned short* __restrict__ wot) {
    int g = blockIdx.x * 256 + threadIdx.x;
    int oc = g & 31, idx = g >> 5;
    float v = (oc < 27) ? ow[idx * 27 + oc] : 0.f;
    wot[oc * 2304 + idx] = f2bf(v);
}

// offset conv, LDS-free: A-frags straight from padded x_p rows. 16 px x 32 oc per block.
__global__ __launch_bounds__(128) void offset_mfma2(const unsigned short* __restrict__ xp,
        const unsigned short* __restrict__ wot, const float* __restrict__ ob,
        float* __restrict__ om) {
    int tid = threadIdx.x;
    int lane = tid & 63;
    int nb = tid >> 6;                 // oc half
    int p0 = blockIdx.x * 16;
    int n  = p0 >> 12;
    int y  = (p0 & 4095) >> 6;
    int w0 = p0 & 63;
    const unsigned short* xpn = xp + (size_t)n * 4489 * 256;
    int ar = lane & 15;
    int kl = (lane >> 4) * 8;
    const unsigned short* bbase = wot + (size_t)(nb * 16 + ar) * 2304 + kl;
    f32x4 acc0 = {0.f,0.f,0.f,0.f}, acc1 = {0.f,0.f,0.f,0.f};
    #pragma unroll
    for (int t = 0; t < 9; ++t) {
        int ty = t / 3, tx = t - 3 * ty;
        const unsigned short* ap = xpn + ((size_t)((y + ty) * 67 + (w0 + ar + tx)) << 8) + kl;
        const unsigned short* bp = bbase + t * 256;
        #pragma unroll
        for (int c0 = 0; c0 < 256; c0 += 32) {
            bf16x8 a = *(const bf16x8*)(ap + c0);
            bf16x8 b = *(const bf16x8*)(bp + c0);
            if (t < 5) acc0 = __builtin_amdgcn_mfma_f32_16x16x32_bf16(a, b, acc0, 0, 0, 0);
            else       acc1 = __builtin_amdgcn_mfma_f32_16x16x32_bf16(a, b, acc1, 0, 0, 0);
        }
    }
    int col = nb * 16 + ar;
    float bias = (col < 27) ? ob[col] : 0.f;
    int rbase = (lane >> 4) * 4;
    #pragma unroll
    for (int j = 0; j < 4; ++j)
        om[(size_t)(p0 + rbase + j) * 32 + col] = acc0[j] + acc1[j] + bias;
}

// Fused bilinear + GEMM, T14 pipeline. 32 px x 256 oc, 512 threads (8 waves).
__global__ __launch_bounds__(512, 2) void dcn_mfma2(const unsigned short* __restrict__ xp,
        const float* __restrict__ om, const unsigned short* __restrict__ wt,
        float* __restrict__ out) {
    __shared__ unsigned int s_v[2][32 * 128];     // [buf][px][256ch bf16], XOR-swizzled 16B
    __shared__ float s_ly[32][9], s_lx[32][9], s_m[32][9];
    __shared__ int   s_y1[32][9], s_x1[32][9];

    int tid  = threadIdx.x;
    int lane = tid & 63;
    int wave = tid >> 6;
    int p0 = blockIdx.x * 32;
    int n  = p0 >> 12;
    int y  = (p0 & 4095) >> 6;
    int w0 = p0 & 63;
    const unsigned short* xpn = xp + (size_t)n * 4489 * 256;

    // Phase A: tap params (padded coords, no bounds math needed later)
    if (tid < 288) {
        int ps = tid / 9, k = tid - 9 * ps;
        int p  = p0 + ps;
        float offy = om[(size_t)p * 32 + 2 * k];
        float offx = om[(size_t)p * 32 + 2 * k + 1];
        float mraw = om[(size_t)p * 32 + 18 + k];
        float mask = 1.f / (1.f + __expf(-mraw));
        float py = (float)(y + 1)       + (float)(k / 3 - 1) + offy;
        float px = (float)(w0 + ps + 1) + (float)(k % 3 - 1) + offx;
        py = fminf(fmaxf(py, 0.f), 65.f);
        px = fminf(fmaxf(px, 0.f), 65.f);
        float y1f = floorf(py), x1f = floorf(px);
        s_y1[ps][k] = (int)y1f;            // padded row [0,65]
        s_x1[ps][k] = (int)x1f;
        s_ly[ps][k] = py - y1f;
        s_lx[ps][k] = px - x1f;
        s_m [ps][k] = mask;
    }
    __syncthreads();

    int cq  = tid & 63;        // channel quad: ch = cq*4
    int grp = wave;            // 4 px per wave-group
    int px0 = grp * 4;
    int ar  = lane & 15;
    int kl  = (lane >> 4) * 8;
    int m   = wave >> 2;       // px half for MFMA
    int nq  = wave & 3;        // 64-oc group

    f32x4 acc[4];
    #pragma unroll
    for (int nf = 0; nf < 4; ++nf) acc[nf] = (f32x4){0.f,0.f,0.f,0.f};

    uint2 st[4][4];

    auto ISSUE = [&](int t) {
        #pragma unroll
        for (int ps = 0; ps < 4; ++ps) {
            int px = px0 + ps;
            int y1 = s_y1[px][t], x1 = s_x1[px][t];
            const unsigned short* b = xpn + ((size_t)(y1 * 67 + x1) << 8) + cq * 4;
            st[ps][0] = *(const uint2*)(b);
            st[ps][1] = *(const uint2*)(b + 256);
            st[ps][2] = *(const uint2*)(b + 17152);
            st[ps][3] = *(const uint2*)(b + 17408);
        }
    };
    auto MATH = [&](int t, int buf) {
        #pragma unroll
        for (int ps = 0; ps < 4; ++ps) {
            int px = px0 + ps;
            float ly = s_ly[px][t], lx = s_lx[px][t], mk = s_m[px][t];
            float hy = 1.f - ly, hx = 1.f - lx;
            float w11 = hy*hx, w12 = hy*lx, w21 = ly*hx, w22 = ly*lx;
            float r0 = mk * (w11*bflo(st[ps][0].x) + w12*bflo(st[ps][1].x) + w21*bflo(st[ps][2].x) + w22*bflo(st[ps][3].x));
            float r1 = mk * (w11*bfhi(st[ps][0].x) + w12*bfhi(st[ps][1].x) + w21*bfhi(st[ps][2].x) + w22*bfhi(st[ps][3].x));
            float r2 = mk * (w11*bflo(st[ps][0].y) + w12*bflo(st[ps][1].y) + w21*bflo(st[ps][2].y) + w22*bflo(st[ps][3].y));
            float r3 = mk * (w11*bfhi(st[ps][0].y) + w12*bfhi(st[ps][1].y) + w21*bfhi(st[ps][2].y) + w22*bfhi(st[ps][3].y));
            unsigned u0 = (unsigned)f2bf(r0) | ((unsigned)f2bf(r1) << 16);
            unsigned u1 = (unsigned)f2bf(r2) | ((unsigned)f2bf(r3) << 16);
            int idx = px * 128 + ((cq * 2) ^ ((px & 7) << 2));
            *(uint2*)&s_v[buf][idx] = make_uint2(u0, u1);
        }
    };
    auto MFMA_PH = [&](int t, int buf) {
        const unsigned short* bp = wt + (size_t)(nq * 64 + ar) * 2304 + kl + t * 256;
        #pragma unroll
        for (int c0 = 0; c0 < 256; c0 += 32) {
            int kb = ((c0 + kl) * 2) ^ ((ar & 7) << 4);
            bf16x8 a = *(const bf16x8*)((const char*)&s_v[buf][0] + (m * 16 + ar) * 512 + kb);
            #pragma unroll
            for (int nf = 0; nf < 4; ++nf) {
                bf16x8 b = *(const bf16x8*)(bp + nf * 36864 + c0);
                acc[nf] = __builtin_amdgcn_mfma_f32_16x16x32_bf16(a, b, acc[nf], 0, 0, 0);
            }
        }
    };

    ISSUE(0);
    MATH(0, 0);
    __syncthreads();
    for (int t = 0; t < 9; ++t) {
        int buf = t & 1;
        if (t < 8) ISSUE(t + 1);
        MFMA_PH(t, buf);
        if (t < 8) MATH(t + 1, buf ^ 1);
        __syncthreads();
    }

    // Epilogue: C/D col=lane&15, row=(lane>>4)*4+j
    int rj = (lane >> 4) * 4;
    #pragma unroll
    for (int nf = 0; nf < 4; ++nf)
        #pragma unroll
        for (int j = 0; j < 4; ++j)
            out[(size_t)(p0 + m * 16 + rj + j) * 256 + nq * 64 + nf * 16 + ar] = acc[nf][j];
}

extern "C" void kernel_launch(void* const* d_in, const int* in_sizes, int n_in,
                              void* d_out, int out_size, void* d_ws, size_t ws_size,
                              hipStream_t stream) {
    const float* x  = (const float*)d_in[0];
    const float* ow = (const float*)d_in[1];
    const float* ob = (const float*)d_in[2];
    const float* dw = (const float*)d_in[3];
    unsigned short* xpp = (unsigned short*)((char*)d_ws + XP_OFF);
    unsigned short* wt  = (unsigned short*)((char*)d_ws + WT_OFF);
    unsigned short* wot = (unsigned short*)((char*)d_ws + WOT_OFF);
    float*          omp = (float*)((char*)d_ws + OM_OFF);
    float* out = (float*)d_out;

    hipLaunchKernelGGL(prep_xpad,    dim3(2245), dim3(256), 0, stream, x, xpp);
    hipLaunchKernelGGL(prep_wt,      dim3(256),  dim3(256), 0, stream, dw, wt);
    hipLaunchKernelGGL(prep_wot,     dim3(288),  dim3(256), 0, stream, ow, wot);
    hipLaunchKernelGGL(offset_mfma2, dim3(1024), dim3(128), 0, stream, xpp, wot, ob, omp);
    hipLaunchKernelGGL(dcn_mfma2,    dim3(512),  dim3(512), 0, stream, xpp, omp, wt, out);
}

// Round 4
// 188.905 us; speedup vs baseline: 3.9552x; 1.0578x over previous
//
#include <hip/hip_runtime.h>
#include <hip/hip_fp16.h>
#include <math.h>

typedef __attribute__((ext_vector_type(8))) _Float16 f16x8;
typedef __attribute__((ext_vector_type(4))) float f32x4;

// x (4,64,64,256) f32 | offset_w (3,3,256,27) | offset_b (27) | dcn_weight (256,256,3,3)
// out (4,64,64,256) f32
// ws layout (bytes):
#define XP_OFF   0                        // x_p f16 [4][67][67][256], pad top/left 1, bot/right 2
#define XP_BYTES (4*67*67*256*2)          // 9,193,472
#define WT_OFF   XP_BYTES                 // W_t f16 [256 oc][2304 k], k = t*256+c
#define WT_BYTES (2304*256*2)
#define WOT_OFF  (WT_OFF + WT_BYTES)      // W_o_t f16 [32 oc][2304 k]
#define WOT_BYTES (2304*32*2)
#define OM_OFF   (WOT_OFF + WOT_BYTES)    // om f32 [16384][32]

// x_p[n][yy][xx][c] = f16(x[n][yy-1][xx-1][c]) for 1<=yy,xx<=64 else 0
__global__ __launch_bounds__(256) void prep_xpad(const float* __restrict__ x,
                                                 __half* __restrict__ xp) {
    int g = blockIdx.x * 256 + threadIdx.x;
    if (g >= 17956 * 32) return;
    int row = g >> 5, sub = g & 31;          // 8 ch per thread
    int n = row / 4489, rem = row - n * 4489;
    int yy = rem / 67,  xx = rem - yy * 67;
    __half* dst = xp + (size_t)row * 256 + sub * 8;
    union { uint4 u; __half2 h[4]; } r;
    r.u = make_uint4(0u, 0u, 0u, 0u);
    if (yy >= 1 && yy <= 64 && xx >= 1 && xx <= 64) {
        const float* src = x + (((size_t)n * 64 + (yy - 1)) * 64 + (xx - 1)) * 256 + sub * 8;
        float4 a = *(const float4*)src;
        float4 b = *(const float4*)(src + 4);
        r.h[0] = __float22half2_rn(make_float2(a.x, a.y));
        r.h[1] = __float22half2_rn(make_float2(a.z, a.w));
        r.h[2] = __float22half2_rn(make_float2(b.x, b.y));
        r.h[3] = __float22half2_rn(make_float2(b.z, b.w));
    }
    *(uint4*)dst = r.u;
}

// W_t[oc][t*256+c] = f16(dcn_w[oc][c][t])
__global__ void prep_wt(const float* __restrict__ dw, __half* __restrict__ wt) {
    int oc = blockIdx.x, c = threadIdx.x;
    const float* src = dw + oc * 2304 + c * 9;
    __half* dst = wt + oc * 2304 + c;
    #pragma unroll
    for (int t = 0; t < 9; ++t) dst[t * 256] = __float2half(src[t]);
}

// W_o_t[oc][t*256+c] = f16(offset_w[(t*256+c)*27 + oc]), oc>=27 -> 0
__global__ void prep_wot(const float* __restrict__ ow, __half* __restrict__ wot) {
    int g = blockIdx.x * 256 + threadIdx.x;
    int oc = g & 31, idx = g >> 5;
    float v = (oc < 27) ? ow[idx * 27 + oc] : 0.f;
    wot[oc * 2304 + idx] = __float2half(v);
}

// offset conv, LDS-free: A-frags straight from padded x_p rows. 16 px x 32 oc per block.
__global__ __launch_bounds__(128) void offset_mfma3(const __half* __restrict__ xp,
        const __half* __restrict__ wot, const float* __restrict__ ob,
        float* __restrict__ om) {
    int tid = threadIdx.x;
    int lane = tid & 63;
    int nb = tid >> 6;                 // oc half
    int bid = blockIdx.x;
    int swz = (bid & 7) * 128 + (bid >> 3);   // 1024 blocks, bijective
    int p0 = swz * 16;
    int n  = p0 >> 12;
    int y  = (p0 & 4095) >> 6;
    int w0 = p0 & 63;
    const __half* xpn = xp + (size_t)n * 4489 * 256;
    int ar = lane & 15;
    int kl = (lane >> 4) * 8;
    const __half* bbase = wot + (size_t)(nb * 16 + ar) * 2304 + kl;
    f32x4 acc0 = {0.f,0.f,0.f,0.f}, acc1 = {0.f,0.f,0.f,0.f};
    #pragma unroll
    for (int t = 0; t < 9; ++t) {
        int ty = t / 3, tx = t - 3 * ty;
        const __half* ap = xpn + ((size_t)((y + ty) * 67 + (w0 + ar + tx)) << 8) + kl;
        const __half* bp = bbase + t * 256;
        #pragma unroll
        for (int c0 = 0; c0 < 256; c0 += 32) {
            f16x8 a = *(const f16x8*)(ap + c0);
            f16x8 b = *(const f16x8*)(bp + c0);
            if (t < 5) acc0 = __builtin_amdgcn_mfma_f32_16x16x32_f16(a, b, acc0, 0, 0, 0);
            else       acc1 = __builtin_amdgcn_mfma_f32_16x16x32_f16(a, b, acc1, 0, 0, 0);
        }
    }
    int col = nb * 16 + ar;
    float bias = (col < 27) ? ob[col] : 0.f;
    int rbase = (lane >> 4) * 4;
    #pragma unroll
    for (int j = 0; j < 4; ++j)
        om[(size_t)(p0 + rbase + j) * 32 + col] = acc0[j] + acc1[j] + bias;
}

// Fused bilinear + GEMM. 16 px x 256 oc, 512 threads (8 waves, each 16px x 32oc).
// 1024 blocks -> 4 blocks/CU, 32 waves/CU. Single-buffer LDS; TLP hides latency.
__global__ __launch_bounds__(512) void dcn_mfma3(const __half* __restrict__ xp,
        const float* __restrict__ om, const __half* __restrict__ wt,
        float* __restrict__ out) {
    __shared__ char  s_v[16 * 512];               // [16 px][256 ch f16], XOR-swizzled 16B
    __shared__ float s_ly[16][9], s_lx[16][9], s_m[16][9];
    __shared__ int   s_y1[16][9], s_x1[16][9];

    int tid  = threadIdx.x;
    int lane = tid & 63;
    int wave = tid >> 6;
    int bid  = blockIdx.x;
    int swzb = (bid & 7) * 128 + (bid >> 3);      // XCD-bijective (1024 % 8 == 0)
    int p0 = swzb * 16;
    int n  = p0 >> 12;
    int y  = (p0 & 4095) >> 6;
    int w0 = p0 & 63;
    const __half* xpn = xp + (size_t)n * 4489 * 256;

    // Phase A: tap params (16 px x 9 taps), padded coords
    if (tid < 144) {
        int ps = tid / 9, k = tid - 9 * ps;
        int p  = p0 + ps;
        float offy = om[(size_t)p * 32 + 2 * k];
        float offx = om[(size_t)p * 32 + 2 * k + 1];
        float mraw = om[(size_t)p * 32 + 18 + k];
        float mask = 1.f / (1.f + __expf(-mraw));
        float py = (float)(y + 1)       + (float)(k / 3 - 1) + offy;
        float px = (float)(w0 + ps + 1) + (float)(k % 3 - 1) + offx;
        py = fminf(fmaxf(py, 0.f), 65.f);
        px = fminf(fmaxf(px, 0.f), 65.f);
        float y1f = floorf(py), x1f = floorf(px);
        s_y1[ps][k] = (int)y1f;
        s_x1[ps][k] = (int)x1f;
        s_ly[ps][k] = py - y1f;
        s_lx[ps][k] = px - x1f;
        s_m [ps][k] = mask;
    }
    __syncthreads();

    int px = tid >> 5;             // staging pixel 0..15
    int ch = (tid & 31) * 8;       // staging channel base
    int ar = lane & 15;
    int kl = (lane >> 4) * 8;
    int oc0 = wave * 32;
    const __half* bp0 = wt + (size_t)(oc0 + ar) * 2304 + kl;
    const __half* bp1 = wt + (size_t)(oc0 + 16 + ar) * 2304 + kl;
    int wr_off = px * 512 + (((tid & 31) * 16) ^ ((px & 7) << 4));
    int rd_row = ar * 512;
    int rd_swz = (ar & 7) << 4;

    f32x4 acc0 = {0.f,0.f,0.f,0.f}, acc1 = {0.f,0.f,0.f,0.f};

    for (int t = 0; t < 9; ++t) {
        // Stage: 4 corner loads (16B each, coalesced 512B/wave) + packed-f16 bilinear
        int y1 = s_y1[px][t], x1 = s_x1[px][t];
        const __half* b = xpn + ((size_t)(y1 * 67 + x1) << 8) + ch;
        union { uint4 u; __half2 h[4]; } cA, cB, cC, cD, r;
        cA.u = *(const uint4*)(b);
        cB.u = *(const uint4*)(b + 256);
        cC.u = *(const uint4*)(b + 17152);
        cD.u = *(const uint4*)(b + 17408);
        float ly = s_ly[px][t], lx = s_lx[px][t], mk = s_m[px][t];
        float hy = 1.f - ly, hx = 1.f - lx;
        __half2 W11 = __float2half2_rn(hy * hx * mk);
        __half2 W12 = __float2half2_rn(hy * lx * mk);
        __half2 W21 = __float2half2_rn(ly * hx * mk);
        __half2 W22 = __float2half2_rn(ly * lx * mk);
        #pragma unroll
        for (int i = 0; i < 4; ++i)
            r.h[i] = __hfma2(cD.h[i], W22, __hfma2(cC.h[i], W21,
                     __hfma2(cB.h[i], W12, __hmul2(cA.h[i], W11))));
        *(uint4*)(s_v + wr_off) = r.u;
        __syncthreads();

        // MFMA: 8 K-steps x 2 N-frags
        const __half* b0 = bp0 + t * 256;
        const __half* b1 = bp1 + t * 256;
        #pragma unroll
        for (int c0 = 0; c0 < 256; c0 += 32) {
            f16x8 a   = *(const f16x8*)(s_v + rd_row + (((c0 + kl) * 2) ^ rd_swz));
            f16x8 vb0 = *(const f16x8*)(b0 + c0);
            f16x8 vb1 = *(const f16x8*)(b1 + c0);
            acc0 = __builtin_amdgcn_mfma_f32_16x16x32_f16(a, vb0, acc0, 0, 0, 0);
            acc1 = __builtin_amdgcn_mfma_f32_16x16x32_f16(a, vb1, acc1, 0, 0, 0);
        }
        __syncthreads();      // before next tap overwrites s_v
    }

    // Epilogue: C/D col=lane&15, row=(lane>>4)*4+j
    int rj = (lane >> 4) * 4;
    #pragma unroll
    for (int j = 0; j < 4; ++j) {
        out[(size_t)(p0 + rj + j) * 256 + oc0 + ar]      = acc0[j];
        out[(size_t)(p0 + rj + j) * 256 + oc0 + 16 + ar] = acc1[j];
    }
}

extern "C" void kernel_launch(void* const* d_in, const int* in_sizes, int n_in,
                              void* d_out, int out_size, void* d_ws, size_t ws_size,
                              hipStream_t stream) {
    const float* x  = (const float*)d_in[0];
    const float* ow = (const float*)d_in[1];
    const float* ob = (const float*)d_in[2];
    const float* dw = (const float*)d_in[3];
    __half* xpp = (__half*)((char*)d_ws + XP_OFF);
    __half* wt  = (__half*)((char*)d_ws + WT_OFF);
    __half* wot = (__half*)((char*)d_ws + WOT_OFF);
    float*  omp = (float*)((char*)d_ws + OM_OFF);
    float* out = (float*)d_out;

    hipLaunchKernelGGL(prep_xpad,    dim3(2245), dim3(256), 0, stream, x, xpp);
    hipLaunchKernelGGL(prep_wt,      dim3(256),  dim3(256), 0, stream, dw, wt);
    hipLaunchKernelGGL(prep_wot,     dim3(288),  dim3(256), 0, stream, ow, wot);
    hipLaunchKernelGGL(offset_mfma3, dim3(1024), dim3(128), 0, stream, xpp, wot, ob, omp);
    hipLaunchKernelGGL(dcn_mfma3,    dim3(1024), dim3(512), 0, stream, xpp, omp, wt, out);
}

// Round 5
// 107.696 us; speedup vs baseline: 6.9377x; 1.7541x over previous
//
#include <hip/hip_runtime.h>
#include <hip/hip_fp16.h>
#include <math.h>

typedef __attribute__((ext_vector_type(8))) _Float16 f16x8;
typedef __attribute__((ext_vector_type(4))) float f32x4;

// x (4,64,64,256) f32 | offset_w (3,3,256,27) | offset_b (27) | dcn_weight (256,256,3,3)
// out (4,64,64,256) f32
// ws layout (bytes):
#define XP_OFF   0                        // x_p f16 [4][67][67][256], pad top/left 1, bot/right 2
#define XP_BYTES (4*67*67*256*2)          // 9,193,472
#define WT_OFF   XP_BYTES                 // W_t f16 [256 oc][2304 k], k = t*256+c
#define WT_BYTES (2304*256*2)
#define WOT_OFF  (WT_OFF + WT_BYTES)      // W_o_t f16 [32 oc][2304 k]
#define WOT_BYTES (2304*32*2)
#define OM_OFF   (WOT_OFF + WOT_BYTES)    // om f32 [16384][32]
#define OM_BYTES (16384*32*4)
#define V_OFF    (OM_OFF + OM_BYTES)      // V f16 [16384 px][2304 k]
#define V_BYTES  ((size_t)16384*2304*2)   // 75,497,472
#define WS_NEED  ((size_t)V_OFF + V_BYTES)

#define AS1(p) ((const __attribute__((address_space(1))) void*)(p))
#define AS3(p) ((__attribute__((address_space(3))) void*)(p))

// ---------- merged prep: x pad+f16, W_t, W_o_t ----------
__global__ __launch_bounds__(256) void prep_all(const float* __restrict__ x,
        const float* __restrict__ dw, const float* __restrict__ ow,
        __half* __restrict__ xp, __half* __restrict__ wt, __half* __restrict__ wot) {
    int b = blockIdx.x, tid = threadIdx.x;
    if (b < 2245) {                               // x_p
        int g = b * 256 + tid;
        if (g >= 17956 * 32) return;
        int row = g >> 5, sub = g & 31;
        int n = row / 4489, rem = row - n * 4489;
        int yy = rem / 67,  xx = rem - yy * 67;
        __half* dst = xp + (size_t)row * 256 + sub * 8;
        union { uint4 u; __half2 h[4]; } r;
        r.u = make_uint4(0u, 0u, 0u, 0u);
        if (yy >= 1 && yy <= 64 && xx >= 1 && xx <= 64) {
            const float* src = x + (((size_t)n * 64 + (yy - 1)) * 64 + (xx - 1)) * 256 + sub * 8;
            float4 a = *(const float4*)src;
            float4 c = *(const float4*)(src + 4);
            r.h[0] = __float22half2_rn(make_float2(a.x, a.y));
            r.h[1] = __float22half2_rn(make_float2(a.z, a.w));
            r.h[2] = __float22half2_rn(make_float2(c.x, c.y));
            r.h[3] = __float22half2_rn(make_float2(c.z, c.w));
        }
        *(uint4*)dst = r.u;
    } else if (b < 2501) {                        // W_t[oc][t*256+c] = dcn_w[oc][c][t]
        int oc = b - 2245, c = tid;
        const float* src = dw + oc * 2304 + c * 9;
        __half* dst = wt + oc * 2304 + c;
        #pragma unroll
        for (int t = 0; t < 9; ++t) dst[t * 256] = __float2half(src[t]);
    } else {                                      // W_o_t
        int g = (b - 2501) * 256 + tid;           // < 73728
        int oc = g & 31, idx = g >> 5;
        float v = (oc < 27) ? ow[idx * 27 + oc] : 0.f;
        wot[oc * 2304 + idx] = __float2half(v);
    }
}

// ---------- offset conv (LDS-free MFMA), 16 px x 32 oc per block ----------
__global__ __launch_bounds__(128) void offset_mfma3(const __half* __restrict__ xp,
        const __half* __restrict__ wot, const float* __restrict__ ob,
        float* __restrict__ om) {
    int tid = threadIdx.x;
    int lane = tid & 63;
    int nb = tid >> 6;
    int bid = blockIdx.x;
    int swz = (bid & 7) * 128 + (bid >> 3);
    int p0 = swz * 16;
    int n  = p0 >> 12;
    int y  = (p0 & 4095) >> 6;
    int w0 = p0 & 63;
    const __half* xpn = xp + (size_t)n * 4489 * 256;
    int ar = lane & 15;
    int kl = (lane >> 4) * 8;
    const __half* bbase = wot + (size_t)(nb * 16 + ar) * 2304 + kl;
    f32x4 acc0 = {0.f,0.f,0.f,0.f}, acc1 = {0.f,0.f,0.f,0.f};
    #pragma unroll
    for (int t = 0; t < 9; ++t) {
        int ty = t / 3, tx = t - 3 * ty;
        const __half* ap = xpn + ((size_t)((y + ty) * 67 + (w0 + ar + tx)) << 8) + kl;
        const __half* bp = bbase + t * 256;
        #pragma unroll
        for (int c0 = 0; c0 < 256; c0 += 32) {
            f16x8 a = *(const f16x8*)(ap + c0);
            f16x8 bb = *(const f16x8*)(bp + c0);
            if (t < 5) acc0 = __builtin_amdgcn_mfma_f32_16x16x32_f16(a, bb, acc0, 0, 0, 0);
            else       acc1 = __builtin_amdgcn_mfma_f32_16x16x32_f16(a, bb, acc1, 0, 0, 0);
        }
    }
    int col = nb * 16 + ar;
    float bias = (col < 27) ? ob[col] : 0.f;
    int rbase = (lane >> 4) * 4;
    #pragma unroll
    for (int j = 0; j < 4; ++j)
        om[(size_t)(p0 + rbase + j) * 32 + col] = acc0[j] + acc1[j] + bias;
}

// ---------- sampler: V[p][t*256+c] = mask * bilinear(x_p) ----------
// thread = (job = p*9+t, s = ch-octet). Pure stream, no barriers/LDS.
__global__ __launch_bounds__(256) void sample_v(const __half* __restrict__ xp,
        const float* __restrict__ om, __half* __restrict__ V) {
    int g = blockIdx.x * 256 + threadIdx.x;   // < 4,718,592
    int j = g >> 5;
    int s = g & 31;
    int p = j / 9;
    int t = j - p * 9;
    int n = p >> 12, y = (p >> 6) & 63, w = p & 63;
    const float* omp = om + (size_t)p * 32;
    float offy = omp[2 * t];
    float offx = omp[2 * t + 1];
    float mraw = omp[18 + t];
    float mask = 1.f / (1.f + __expf(-mraw));
    float py = (float)(y + 1) + (float)(t / 3 - 1) + offy;
    float px = (float)(w + 1) + (float)(t % 3 - 1) + offx;
    py = fminf(fmaxf(py, 0.f), 65.f);
    px = fminf(fmaxf(px, 0.f), 65.f);
    float y1f = floorf(py), x1f = floorf(px);
    int y1 = (int)y1f, x1 = (int)x1f;
    float ly = py - y1f, lx = px - x1f, hy = 1.f - ly, hx = 1.f - lx;
    const __half* b = xp + (size_t)n * 4489 * 256 + ((y1 * 67 + x1) << 8) + s * 8;
    union { uint4 u; __half2 h[4]; } cA, cB, cC, cD, r;
    cA.u = *(const uint4*)(b);
    cB.u = *(const uint4*)(b + 256);
    cC.u = *(const uint4*)(b + 17152);     // +1 row (67*256)
    cD.u = *(const uint4*)(b + 17408);
    __half2 W11 = __float2half2_rn(hy * hx * mask), W12 = __float2half2_rn(hy * lx * mask);
    __half2 W21 = __float2half2_rn(ly * hx * mask), W22 = __float2half2_rn(ly * lx * mask);
    #pragma unroll
    for (int i = 0; i < 4; ++i)
        r.h[i] = __hfma2(cD.h[i], W22, __hfma2(cC.h[i], W21,
                 __hfma2(cB.h[i], W12, __hmul2(cA.h[i], W11))));
    *(uint4*)((char*)V + (size_t)g * 16) = r.u;   // flat linear store
}

// ---------- GEMM: out[16384,256] = V[16384,2304] x W_t[256,2304]^T ----------
// 128x128 tile, BK=64, 4 waves (2x2, each 64x64 = 4x4 frags), double-buffered
// global_load_lds(16B) with XOR-pre-swizzled source (T2 via m173).
__global__ __launch_bounds__(256) void gemm_v(const __half* __restrict__ V,
        const __half* __restrict__ wt, float* __restrict__ out) {
    __shared__ __align__(16) char sA[2][16384];   // [128 row][64 k] f16, swizzled
    __shared__ __align__(16) char sB[2][16384];
    int tid = threadIdx.x, lane = tid & 63, wave = tid >> 6;
    int bid = blockIdx.x;
    // XCD-local: XCD k = bid&7 owns M-stripe [k*2048, (k+1)*2048) px, both N-tiles
    int i8 = bid >> 3;
    int mt = (bid & 7) * 16 + (i8 >> 1);
    int nt = i8 & 1;
    int p0 = mt * 128, oc0 = nt * 128;
    int wr = wave >> 1, wc = wave & 1;
    int ar = lane & 15, kl = (lane >> 4) * 8;

    // staging source addrs: inst q covers rows wave*32+q*8 .. +7
    int lrow = lane >> 3;
    int lxor = ((lane & 7) * 16) ^ ((lrow & 7) << 4);
    const char* aS[4]; const char* bS[4];
    #pragma unroll
    for (int q = 0; q < 4; ++q) {
        int r = wave * 32 + q * 8 + lrow;
        aS[q] = (const char*)V  + ((size_t)(p0  + r) * 2304) * 2 + lxor;
        bS[q] = (const char*)wt + ((size_t)(oc0 + r) * 2304) * 2 + lxor;
    }

    f32x4 acc[4][4];
    #pragma unroll
    for (int m = 0; m < 4; ++m)
        #pragma unroll
        for (int n = 0; n < 4; ++n) acc[m][n] = (f32x4){0.f,0.f,0.f,0.f};

    #pragma unroll
    for (int q = 0; q < 4; ++q) {
        __builtin_amdgcn_global_load_lds(AS1(aS[q]), AS3(&sA[0][(wave * 4 + q) * 1024]), 16, 0, 0);
        __builtin_amdgcn_global_load_lds(AS1(bS[q]), AS3(&sB[0][(wave * 4 + q) * 1024]), 16, 0, 0);
    }
    __syncthreads();

    for (int kt = 0; kt < 36; ++kt) {
        int buf = kt & 1;
        if (kt < 35) {
            int kb = (kt + 1) * 128;
            #pragma unroll
            for (int q = 0; q < 4; ++q) {
                __builtin_amdgcn_global_load_lds(AS1(aS[q] + kb), AS3(&sA[buf ^ 1][(wave * 4 + q) * 1024]), 16, 0, 0);
                __builtin_amdgcn_global_load_lds(AS1(bS[q] + kb), AS3(&sB[buf ^ 1][(wave * 4 + q) * 1024]), 16, 0, 0);
            }
        }
        const char* sa = &sA[buf][0];
        const char* sb = &sB[buf][0];
        #pragma unroll
        for (int kk = 0; kk < 2; ++kk) {
            int ko = (kk * 64 + kl * 2) ^ ((ar & 7) << 4);
            f16x8 af[4], bf[4];
            #pragma unroll
            for (int m = 0; m < 4; ++m)
                af[m] = *(const f16x8*)(sa + (wr * 64 + m * 16 + ar) * 128 + ko);
            #pragma unroll
            for (int n = 0; n < 4; ++n)
                bf[n] = *(const f16x8*)(sb + (wc * 64 + n * 16 + ar) * 128 + ko);
            #pragma unroll
            for (int m = 0; m < 4; ++m)
                #pragma unroll
                for (int n = 0; n < 4; ++n)
                    acc[m][n] = __builtin_amdgcn_mfma_f32_16x16x32_f16(af[m], bf[n], acc[m][n], 0, 0, 0);
        }
        __syncthreads();
    }

    // C/D: col=lane&15 (oc), row=(lane>>4)*4+j (px)
    int rj = (lane >> 4) * 4;
    #pragma unroll
    for (int m = 0; m < 4; ++m)
        #pragma unroll
        for (int n = 0; n < 4; ++n)
            #pragma unroll
            for (int j = 0; j < 4; ++j)
                out[(size_t)(p0 + wr * 64 + m * 16 + rj + j) * 256 + oc0 + wc * 64 + n * 16 + ar] = acc[m][n][j];
}

// ---------- fallback fused kernel (round-4) if ws too small ----------
__global__ __launch_bounds__(512) void dcn_mfma3(const __half* __restrict__ xp,
        const float* __restrict__ om, const __half* __restrict__ wt,
        float* __restrict__ out) {
    __shared__ char  s_v[16 * 512];
    __shared__ float s_ly[16][9], s_lx[16][9], s_m[16][9];
    __shared__ int   s_y1[16][9], s_x1[16][9];
    int tid  = threadIdx.x;
    int lane = tid & 63;
    int wave = tid >> 6;
    int bid  = blockIdx.x;
    int swzb = (bid & 7) * 128 + (bid >> 3);
    int p0 = swzb * 16;
    int n  = p0 >> 12;
    int y  = (p0 & 4095) >> 6;
    int w0 = p0 & 63;
    const __half* xpn = xp + (size_t)n * 4489 * 256;
    if (tid < 144) {
        int ps = tid / 9, k = tid - 9 * ps;
        int p  = p0 + ps;
        float offy = om[(size_t)p * 32 + 2 * k];
        float offx = om[(size_t)p * 32 + 2 * k + 1];
        float mraw = om[(size_t)p * 32 + 18 + k];
        float mask = 1.f / (1.f + __expf(-mraw));
        float py = (float)(y + 1)       + (float)(k / 3 - 1) + offy;
        float px = (float)(w0 + ps + 1) + (float)(k % 3 - 1) + offx;
        py = fminf(fmaxf(py, 0.f), 65.f);
        px = fminf(fmaxf(px, 0.f), 65.f);
        float y1f = floorf(py), x1f = floorf(px);
        s_y1[ps][k] = (int)y1f;
        s_x1[ps][k] = (int)x1f;
        s_ly[ps][k] = py - y1f;
        s_lx[ps][k] = px - x1f;
        s_m [ps][k] = mask;
    }
    __syncthreads();
    int px = tid >> 5;
    int ch = (tid & 31) * 8;
    int ar = lane & 15;
    int kl = (lane >> 4) * 8;
    int oc0 = wave * 32;
    const __half* bp0 = wt + (size_t)(oc0 + ar) * 2304 + kl;
    const __half* bp1 = wt + (size_t)(oc0 + 16 + ar) * 2304 + kl;
    int wr_off = px * 512 + (((tid & 31) * 16) ^ ((px & 7) << 4));
    int rd_row = ar * 512;
    int rd_swz = (ar & 7) << 4;
    f32x4 acc0 = {0.f,0.f,0.f,0.f}, acc1 = {0.f,0.f,0.f,0.f};
    for (int t = 0; t < 9; ++t) {
        int y1 = s_y1[px][t], x1 = s_x1[px][t];
        const __half* b = xpn + ((size_t)(y1 * 67 + x1) << 8) + ch;
        union { uint4 u; __half2 h[4]; } cA, cB, cC, cD, r;
        cA.u = *(const uint4*)(b);
        cB.u = *(const uint4*)(b + 256);
        cC.u = *(const uint4*)(b + 17152);
        cD.u = *(const uint4*)(b + 17408);
        float ly = s_ly[px][t], lx = s_lx[px][t], mk = s_m[px][t];
        float hy = 1.f - ly, hx = 1.f - lx;
        __half2 W11 = __float2half2_rn(hy * hx * mk);
        __half2 W12 = __float2half2_rn(hy * lx * mk);
        __half2 W21 = __float2half2_rn(ly * hx * mk);
        __half2 W22 = __float2half2_rn(ly * lx * mk);
        #pragma unroll
        for (int i = 0; i < 4; ++i)
            r.h[i] = __hfma2(cD.h[i], W22, __hfma2(cC.h[i], W21,
                     __hfma2(cB.h[i], W12, __hmul2(cA.h[i], W11))));
        *(uint4*)(s_v + wr_off) = r.u;
        __syncthreads();
        const __half* b0 = bp0 + t * 256;
        const __half* b1 = bp1 + t * 256;
        #pragma unroll
        for (int c0 = 0; c0 < 256; c0 += 32) {
            f16x8 a   = *(const f16x8*)(s_v + rd_row + (((c0 + kl) * 2) ^ rd_swz));
            f16x8 vb0 = *(const f16x8*)(b0 + c0);
            f16x8 vb1 = *(const f16x8*)(b1 + c0);
            acc0 = __builtin_amdgcn_mfma_f32_16x16x32_f16(a, vb0, acc0, 0, 0, 0);
            acc1 = __builtin_amdgcn_mfma_f32_16x16x32_f16(a, vb1, acc1, 0, 0, 0);
        }
        __syncthreads();
    }
    int rj = (lane >> 4) * 4;
    #pragma unroll
    for (int j = 0; j < 4; ++j) {
        out[(size_t)(p0 + rj + j) * 256 + oc0 + ar]      = acc0[j];
        out[(size_t)(p0 + rj + j) * 256 + oc0 + 16 + ar] = acc1[j];
    }
}

extern "C" void kernel_launch(void* const* d_in, const int* in_sizes, int n_in,
                              void* d_out, int out_size, void* d_ws, size_t ws_size,
                              hipStream_t stream) {
    const float* x  = (const float*)d_in[0];
    const float* ow = (const float*)d_in[1];
    const float* ob = (const float*)d_in[2];
    const float* dw = (const float*)d_in[3];
    __half* xpp = (__half*)((char*)d_ws + XP_OFF);
    __half* wt  = (__half*)((char*)d_ws + WT_OFF);
    __half* wot = (__half*)((char*)d_ws + WOT_OFF);
    float*  omp = (float*)((char*)d_ws + OM_OFF);
    __half* Vp  = (__half*)((char*)d_ws + V_OFF);
    float* out = (float*)d_out;

    hipLaunchKernelGGL(prep_all,     dim3(2789), dim3(256), 0, stream, x, dw, ow, xpp, wt, wot);
    hipLaunchKernelGGL(offset_mfma3, dim3(1024), dim3(128), 0, stream, xpp, wot, ob, omp);
    if (ws_size >= WS_NEED) {
        hipLaunchKernelGGL(sample_v, dim3(18432), dim3(256), 0, stream, xpp, omp, Vp);
        hipLaunchKernelGGL(gemm_v,   dim3(256),   dim3(256), 0, stream, Vp, wt, out);
    } else {
        hipLaunchKernelGGL(dcn_mfma3, dim3(1024), dim3(512), 0, stream, xpp, omp, wt, out);
    }
}

// Round 6
// 85.113 us; speedup vs baseline: 8.7784x; 1.2653x over previous
//
#include <hip/hip_runtime.h>
#include <hip/hip_fp16.h>
#include <math.h>

typedef __attribute__((ext_vector_type(8))) _Float16 f16x8;
typedef __attribute__((ext_vector_type(4))) float f32x4;

// x (4,64,64,256) f32 | offset_w (3,3,256,27) | offset_b (27) | dcn_weight (256,256,3,3)
// out (4,64,64,256) f32
// ws layout (bytes):
#define XP_OFF   0                        // x_p f16 [4][67][67][256], pad top/left 1, bot/right 2
#define XP_BYTES (4*67*67*256*2)          // 9,193,472
#define WT_OFF   XP_BYTES                 // W_t f16 [256 oc][2304 k], k = t*256+c
#define WT_BYTES (2304*256*2)
#define WOT_OFF  (WT_OFF + WT_BYTES)      // W_o_t f16 [32 oc][2304 k]
#define WOT_BYTES (2304*32*2)
#define OM_OFF   (WOT_OFF + WOT_BYTES)    // om f32 [16384][32]
#define OM_BYTES (16384*32*4)
#define V_OFF    (OM_OFF + OM_BYTES)      // V f16 [16384 px][2304 k]
#define V_BYTES  ((size_t)16384*2304*2)   // 75,497,472
#define WS_NEED  ((size_t)V_OFF + V_BYTES)

#define AS1(p) ((const __attribute__((address_space(1))) void*)(p))
#define AS3(p) ((__attribute__((address_space(3))) void*)(p))

// ---------- merged prep: x pad+f16, W_t, W_o_t ----------
__global__ __launch_bounds__(256) void prep_all(const float* __restrict__ x,
        const float* __restrict__ dw, const float* __restrict__ ow,
        __half* __restrict__ xp, __half* __restrict__ wt, __half* __restrict__ wot) {
    int b = blockIdx.x, tid = threadIdx.x;
    if (b < 2245) {                               // x_p
        int g = b * 256 + tid;
        if (g >= 17956 * 32) return;
        int row = g >> 5, sub = g & 31;
        int n = row / 4489, rem = row - n * 4489;
        int yy = rem / 67,  xx = rem - yy * 67;
        __half* dst = xp + (size_t)row * 256 + sub * 8;
        union { uint4 u; __half2 h[4]; } r;
        r.u = make_uint4(0u, 0u, 0u, 0u);
        if (yy >= 1 && yy <= 64 && xx >= 1 && xx <= 64) {
            const float* src = x + (((size_t)n * 64 + (yy - 1)) * 64 + (xx - 1)) * 256 + sub * 8;
            float4 a = *(const float4*)src;
            float4 c = *(const float4*)(src + 4);
            r.h[0] = __float22half2_rn(make_float2(a.x, a.y));
            r.h[1] = __float22half2_rn(make_float2(a.z, a.w));
            r.h[2] = __float22half2_rn(make_float2(c.x, c.y));
            r.h[3] = __float22half2_rn(make_float2(c.z, c.w));
        }
        *(uint4*)dst = r.u;
    } else if (b < 2501) {                        // W_t[oc][t*256+c] = dcn_w[oc][c][t]
        int oc = b - 2245, c = tid;
        const float* src = dw + oc * 2304 + c * 9;
        __half* dst = wt + oc * 2304 + c;
        #pragma unroll
        for (int t = 0; t < 9; ++t) dst[t * 256] = __float2half(src[t]);
    } else {                                      // W_o_t
        int g = (b - 2501) * 256 + tid;           // < 73728
        int oc = g & 31, idx = g >> 5;
        float v = (oc < 27) ? ow[idx * 27 + oc] : 0.f;
        wot[oc * 2304 + idx] = __float2half(v);
    }
}

// ---------- offset conv: 32 px x 32 oc, A staged via global_load_lds ----------
// A-tile per tap = contiguous 32px x 512B stripe of x_p (taps are axis-aligned).
__global__ __launch_bounds__(256) void offset_mfma4(const __half* __restrict__ xp,
        const __half* __restrict__ wot, const float* __restrict__ ob,
        float* __restrict__ om) {
    __shared__ __align__(16) char sA[2][16384];   // [32 px][512B f16], XOR-swizzled
    int tid = threadIdx.x, lane = tid & 63, wave = tid >> 6;
    int bid = blockIdx.x;
    int mt = (bid & 7) * 64 + (bid >> 3);         // XCD-bijective (512 blocks)
    int p0 = mt * 32;
    int n = p0 >> 12, y = (p0 & 4095) >> 6, w0 = p0 & 63;
    const char* xpn = (const char*)(xp + (size_t)n * 4489 * 256);
    int wr = wave >> 1, wc = wave & 1;
    int ar = lane & 15, kl = (lane >> 4) * 8;

    // staging: 4 insts/thread; dest d=(q*256+tid)*16 (linear), src pre-XOR-swizzled
    int soff[4];
    #pragma unroll
    for (int q = 0; q < 4; ++q) {
        int d = (q * 256 + tid) * 16;
        int row = d >> 9;
        soff[q] = row * 512 + ((d & 511) ^ ((row & 7) << 4));
    }

    f32x4 acc = {0.f, 0.f, 0.f, 0.f};
    int r_a = wr * 16 + ar;
    int rsw = (r_a & 7) << 4;
    const __half* bb = wot + (size_t)(wc * 16 + ar) * 2304 + kl;

    // stripe byte base for tap t (ty=t/3, tx=t%3): (((y+ty)*67 + w0+tx) << 9)
    #pragma unroll
    for (int q = 0; q < 4; ++q)
        __builtin_amdgcn_global_load_lds(AS1(xpn + ((y * 67 + w0) << 9) + soff[q]),
                                         AS3(&sA[0][(q * 256 + tid) * 16]), 16, 0, 0);
    __syncthreads();

    for (int t = 0; t < 9; ++t) {
        int buf = t & 1;
        if (t < 8) {
            int t1 = t + 1;
            int ty = t1 / 3, tx = t1 - 3 * ty;
            int sb = ((y + ty) * 67 + w0 + tx) << 9;
            #pragma unroll
            for (int q = 0; q < 4; ++q)
                __builtin_amdgcn_global_load_lds(AS1(xpn + sb + soff[q]),
                                                 AS3(&sA[buf ^ 1][(q * 256 + tid) * 16]), 16, 0, 0);
        }
        const __half* bp = bb + t * 256;
        #pragma unroll
        for (int c0 = 0; c0 < 256; c0 += 32) {
            f16x8 a = *(const f16x8*)(&sA[buf][0] + r_a * 512 + (((c0 + kl) * 2) ^ rsw));
            f16x8 b = *(const f16x8*)(bp + c0);
            acc = __builtin_amdgcn_mfma_f32_16x16x32_f16(a, b, acc, 0, 0, 0);
        }
        __syncthreads();
    }

    int col = wc * 16 + ar;
    float bias = (col < 27) ? ob[col] : 0.f;
    int rj = (lane >> 4) * 4;
    #pragma unroll
    for (int j = 0; j < 4; ++j)
        om[(size_t)(p0 + wr * 16 + rj + j) * 32 + col] = acc[j] + bias;
}

// ---------- sampler: V[p][t*256+c] = mask * bilinear(x_p) ----------
__global__ __launch_bounds__(256) void sample_v(const __half* __restrict__ xp,
        const float* __restrict__ om, __half* __restrict__ V) {
    int g = blockIdx.x * 256 + threadIdx.x;   // < 4,718,592
    int j = g >> 5;
    int s = g & 31;
    int p = j / 9;
    int t = j - p * 9;
    int n = p >> 12, y = (p >> 6) & 63, w = p & 63;
    const float* omp = om + (size_t)p * 32;
    float offy = omp[2 * t];
    float offx = omp[2 * t + 1];
    float mraw = omp[18 + t];
    float mask = 1.f / (1.f + __expf(-mraw));
    float py = (float)(y + 1) + (float)(t / 3 - 1) + offy;
    float px = (float)(w + 1) + (float)(t % 3 - 1) + offx;
    py = fminf(fmaxf(py, 0.f), 65.f);
    px = fminf(fmaxf(px, 0.f), 65.f);
    float y1f = floorf(py), x1f = floorf(px);
    int y1 = (int)y1f, x1 = (int)x1f;
    float ly = py - y1f, lx = px - x1f, hy = 1.f - ly, hx = 1.f - lx;
    const __half* b = xp + (size_t)n * 4489 * 256 + ((y1 * 67 + x1) << 8) + s * 8;
    union { uint4 u; __half2 h[4]; } cA, cB, cC, cD, r;
    cA.u = *(const uint4*)(b);
    cB.u = *(const uint4*)(b + 256);
    cC.u = *(const uint4*)(b + 17152);     // +1 row (67*256)
    cD.u = *(const uint4*)(b + 17408);
    __half2 W11 = __float2half2_rn(hy * hx * mask), W12 = __float2half2_rn(hy * lx * mask);
    __half2 W21 = __float2half2_rn(ly * hx * mask), W22 = __float2half2_rn(ly * lx * mask);
    #pragma unroll
    for (int i = 0; i < 4; ++i)
        r.h[i] = __hfma2(cD.h[i], W22, __hfma2(cC.h[i], W21,
                 __hfma2(cB.h[i], W12, __hmul2(cA.h[i], W11))));
    *(uint4*)((char*)V + (size_t)g * 16) = r.u;   // flat linear store
}

// ---------- GEMM: out[16384,256] = V[16384,2304] x W_t[256,2304]^T ----------
// 64x128 tile, BK=64, 4 waves (2x2; each 32x64 = 2x4 frags), dbuf 48KB LDS,
// grid 512 = 2 blocks/CU, XCD-bijective with N-pair co-location.
__global__ __launch_bounds__(256) void gemm_v2(const __half* __restrict__ V,
        const __half* __restrict__ wt, float* __restrict__ out) {
    __shared__ __align__(16) char sA[2][8192];    // [64 row][128B]
    __shared__ __align__(16) char sB[2][16384];   // [128 row][128B]
    int tid = threadIdx.x, lane = tid & 63, wave = tid >> 6;
    int bid = blockIdx.x;
    int xcd = bid & 7, idx = bid >> 3;            // 512 blocks
    int mt = xcd * 32 + (idx >> 1);
    int nt = idx & 1;
    int p0 = mt * 64, oc0 = nt * 128;
    int wr = wave >> 1, wc = wave & 1;
    int ar = lane & 15, kl = (lane >> 4) * 8;

    // staging sources (pre-XOR-swizzled, m173); dest linear (q*256+tid)*16
    const char* aS[2]; const char* bS[4];
    #pragma unroll
    for (int q = 0; q < 2; ++q) {
        int d = (q * 256 + tid) * 16;
        int row = d >> 7, wb = d & 127;
        aS[q] = (const char*)V + (size_t)(p0 + row) * 4608 + (wb ^ ((row & 7) << 4));
    }
    #pragma unroll
    for (int q = 0; q < 4; ++q) {
        int d = (q * 256 + tid) * 16;
        int row = d >> 7, wb = d & 127;
        bS[q] = (const char*)wt + (size_t)(oc0 + row) * 4608 + (wb ^ ((row & 7) << 4));
    }

    f32x4 acc[2][4];
    #pragma unroll
    for (int m = 0; m < 2; ++m)
        #pragma unroll
        for (int nn = 0; nn < 4; ++nn) acc[m][nn] = (f32x4){0.f,0.f,0.f,0.f};

    #pragma unroll
    for (int q = 0; q < 2; ++q)
        __builtin_amdgcn_global_load_lds(AS1(aS[q]), AS3(&sA[0][(q * 256 + tid) * 16]), 16, 0, 0);
    #pragma unroll
    for (int q = 0; q < 4; ++q)
        __builtin_amdgcn_global_load_lds(AS1(bS[q]), AS3(&sB[0][(q * 256 + tid) * 16]), 16, 0, 0);
    __syncthreads();

    for (int kt = 0; kt < 36; ++kt) {
        int buf = kt & 1;
        if (kt < 35) {
            int kb = (kt + 1) * 128;
            #pragma unroll
            for (int q = 0; q < 2; ++q)
                __builtin_amdgcn_global_load_lds(AS1(aS[q] + kb), AS3(&sA[buf ^ 1][(q * 256 + tid) * 16]), 16, 0, 0);
            #pragma unroll
            for (int q = 0; q < 4; ++q)
                __builtin_amdgcn_global_load_lds(AS1(bS[q] + kb), AS3(&sB[buf ^ 1][(q * 256 + tid) * 16]), 16, 0, 0);
        }
        #pragma unroll
        for (int kk = 0; kk < 2; ++kk) {
            int ko = kk * 64 + kl * 2;
            f16x8 af[2], bf[4];
            #pragma unroll
            for (int m = 0; m < 2; ++m) {
                int r = wr * 32 + m * 16 + ar;
                af[m] = *(const f16x8*)(&sA[buf][0] + r * 128 + (ko ^ ((r & 7) << 4)));
            }
            #pragma unroll
            for (int nn = 0; nn < 4; ++nn) {
                int r = wc * 64 + nn * 16 + ar;
                bf[nn] = *(const f16x8*)(&sB[buf][0] + r * 128 + (ko ^ ((r & 7) << 4)));
            }
            #pragma unroll
            for (int m = 0; m < 2; ++m)
                #pragma unroll
                for (int nn = 0; nn < 4; ++nn)
                    acc[m][nn] = __builtin_amdgcn_mfma_f32_16x16x32_f16(af[m], bf[nn], acc[m][nn], 0, 0, 0);
        }
        __syncthreads();
    }

    // C/D: col=lane&15 (oc), row=(lane>>4)*4+j (px)
    int rj = (lane >> 4) * 4;
    #pragma unroll
    for (int m = 0; m < 2; ++m)
        #pragma unroll
        for (int nn = 0; nn < 4; ++nn)
            #pragma unroll
            for (int j = 0; j < 4; ++j)
                out[(size_t)(p0 + wr * 32 + m * 16 + rj + j) * 256 + oc0 + wc * 64 + nn * 16 + ar] = acc[m][nn][j];
}

// ---------- fallback fused kernel if ws too small ----------
__global__ __launch_bounds__(512) void dcn_mfma3(const __half* __restrict__ xp,
        const float* __restrict__ om, const __half* __restrict__ wt,
        float* __restrict__ out) {
    __shared__ char  s_v[16 * 512];
    __shared__ float s_ly[16][9], s_lx[16][9], s_m[16][9];
    __shared__ int   s_y1[16][9], s_x1[16][9];
    int tid  = threadIdx.x;
    int lane = tid & 63;
    int wave = tid >> 6;
    int bid  = blockIdx.x;
    int swzb = (bid & 7) * 128 + (bid >> 3);
    int p0 = swzb * 16;
    int n  = p0 >> 12;
    int y  = (p0 & 4095) >> 6;
    int w0 = p0 & 63;
    const __half* xpn = xp + (size_t)n * 4489 * 256;
    if (tid < 144) {
        int ps = tid / 9, k = tid - 9 * ps;
        int p  = p0 + ps;
        float offy = om[(size_t)p * 32 + 2 * k];
        float offx = om[(size_t)p * 32 + 2 * k + 1];
        float mraw = om[(size_t)p * 32 + 18 + k];
        float mask = 1.f / (1.f + __expf(-mraw));
        float py = (float)(y + 1)       + (float)(k / 3 - 1) + offy;
        float px = (float)(w0 + ps + 1) + (float)(k % 3 - 1) + offx;
        py = fminf(fmaxf(py, 0.f), 65.f);
        px = fminf(fmaxf(px, 0.f), 65.f);
        float y1f = floorf(py), x1f = floorf(px);
        s_y1[ps][k] = (int)y1f;
        s_x1[ps][k] = (int)x1f;
        s_ly[ps][k] = py - y1f;
        s_lx[ps][k] = px - x1f;
        s_m [ps][k] = mask;
    }
    __syncthreads();
    int px = tid >> 5;
    int ch = (tid & 31) * 8;
    int ar = lane & 15;
    int kl = (lane >> 4) * 8;
    int oc0 = wave * 32;
    const __half* bp0 = wt + (size_t)(oc0 + ar) * 2304 + kl;
    const __half* bp1 = wt + (size_t)(oc0 + 16 + ar) * 2304 + kl;
    int wr_off = px * 512 + (((tid & 31) * 16) ^ ((px & 7) << 4));
    int rd_row = ar * 512;
    int rd_swz = (ar & 7) << 4;
    f32x4 acc0 = {0.f,0.f,0.f,0.f}, acc1 = {0.f,0.f,0.f,0.f};
    for (int t = 0; t < 9; ++t) {
        int y1 = s_y1[px][t], x1 = s_x1[px][t];
        const __half* b = xpn + ((size_t)(y1 * 67 + x1) << 8) + ch;
        union { uint4 u; __half2 h[4]; } cA, cB, cC, cD, r;
        cA.u = *(const uint4*)(b);
        cB.u = *(const uint4*)(b + 256);
        cC.u = *(const uint4*)(b + 17152);
        cD.u = *(const uint4*)(b + 17408);
        float ly = s_ly[px][t], lx = s_lx[px][t], mk = s_m[px][t];
        float hy = 1.f - ly, hx = 1.f - lx;
        __half2 W11 = __float2half2_rn(hy * hx * mk);
        __half2 W12 = __float2half2_rn(hy * lx * mk);
        __half2 W21 = __float2half2_rn(ly * hx * mk);
        __half2 W22 = __float2half2_rn(ly * lx * mk);
        #pragma unroll
        for (int i = 0; i < 4; ++i)
            r.h[i] = __hfma2(cD.h[i], W22, __hfma2(cC.h[i], W21,
                     __hfma2(cB.h[i], W12, __hmul2(cA.h[i], W11))));
        *(uint4*)(s_v + wr_off) = r.u;
        __syncthreads();
        const __half* b0 = bp0 + t * 256;
        const __half* b1 = bp1 + t * 256;
        #pragma unroll
        for (int c0 = 0; c0 < 256; c0 += 32) {
            f16x8 a   = *(const f16x8*)(s_v + rd_row + (((c0 + kl) * 2) ^ rd_swz));
            f16x8 vb0 = *(const f16x8*)(b0 + c0);
            f16x8 vb1 = *(const f16x8*)(b1 + c0);
            acc0 = __builtin_amdgcn_mfma_f32_16x16x32_f16(a, vb0, acc0, 0, 0, 0);
            acc1 = __builtin_amdgcn_mfma_f32_16x16x32_f16(a, vb1, acc1, 0, 0, 0);
        }
        __syncthreads();
    }
    int rj = (lane >> 4) * 4;
    #pragma unroll
    for (int j = 0; j < 4; ++j) {
        out[(size_t)(p0 + rj + j) * 256 + oc0 + ar]      = acc0[j];
        out[(size_t)(p0 + rj + j) * 256 + oc0 + 16 + ar] = acc1[j];
    }
}

extern "C" void kernel_launch(void* const* d_in, const int* in_sizes, int n_in,
                              void* d_out, int out_size, void* d_ws, size_t ws_size,
                              hipStream_t stream) {
    const float* x  = (const float*)d_in[0];
    const float* ow = (const float*)d_in[1];
    const float* ob = (const float*)d_in[2];
    const float* dw = (const float*)d_in[3];
    __half* xpp = (__half*)((char*)d_ws + XP_OFF);
    __half* wt  = (__half*)((char*)d_ws + WT_OFF);
    __half* wot = (__half*)((char*)d_ws + WOT_OFF);
    float*  omp = (float*)((char*)d_ws + OM_OFF);
    __half* Vp  = (__half*)((char*)d_ws + V_OFF);
    float* out = (float*)d_out;

    hipLaunchKernelGGL(prep_all,     dim3(2789), dim3(256), 0, stream, x, dw, ow, xpp, wt, wot);
    hipLaunchKernelGGL(offset_mfma4, dim3(512),  dim3(256), 0, stream, xpp, wot, ob, omp);
    if (ws_size >= WS_NEED) {
        hipLaunchKernelGGL(sample_v, dim3(18432), dim3(256), 0, stream, xpp, omp, Vp);
        hipLaunchKernelGGL(gemm_v2,  dim3(512),   dim3(256), 0, stream, Vp, wt, out);
    } else {
        hipLaunchKernelGGL(dcn_mfma3, dim3(1024), dim3(512), 0, stream, xpp, omp, wt, out);
    }
}